// Round 5
// baseline (639.763 us; speedup 1.0000x reference)
//
#include <hip/hip_runtime.h>

typedef unsigned int u32;

#define EPS 1e-5f

// One block per batch item b (grid 4096, block 256).
// Inputs: float32 (confirmed R4); mask: 32-bit words, truthiness (confirmed R3);
// output: FLOAT32 (harness reads np.float32 — reference output dtype).
// All intermediates in LDS; no workspace use.
__global__ __launch_bounds__(256) void fused_net_kernel(
        const float* __restrict__ x,    const u32*  __restrict__ mask,
        const float* __restrict__ W1,   const float* __restrict__ g1,
        const float* __restrict__ b1,   const float* __restrict__ m1,
        const float* __restrict__ v1,   const float* __restrict__ W2,
        const float* __restrict__ g2,   const float* __restrict__ b2,
        const float* __restrict__ m2,   const float* __restrict__ v2,
        const float* __restrict__ fcw1, const float* __restrict__ fcb1,
        const float* __restrict__ fcw2, const float* __restrict__ fcb2,
        float* __restrict__ out) {

    __shared__ float xs[2048];       // [ci(4)][site(512)] conv1 input
    __shared__ int   msk[512];       // active-site mask
    __shared__ float hs[32 * 65];    // [ci(32)][s(64)] pooled conv1 out, padded
    __shared__ float mf2s[64];       // pooled mask
    __shared__ float h2s[512];       // [co(64)][pp(8)] pooled conv2 out
    __shared__ float sc1s[32], sh1s[32], sc2s[64], sh2s[64];
    __shared__ float red[4];

    const int b = blockIdx.x;
    const int t = threadIdx.x;

    // ---- BN fold (per block; trivial cost) ----
    if (t < 32) {
        float sc = g1[t] / sqrtf(v1[t] + EPS);
        sc1s[t] = sc; sh1s[t] = b1[t] - m1[t] * sc;
    } else if (t < 96) {
        int c = t - 32;
        float sc = g2[c] / sqrtf(v2[c] + EPS);
        sc2s[c] = sc; sh2s[c] = b2[c] - m2[c] * sc;
    }

    // ---- stage x (2048 f32) and mask (512 words) ----
    {
        const float4* xp = (const float4*)(x + (size_t)b * 2048);
        ((float4*)xs)[t]       = xp[t];
        ((float4*)xs)[t + 256] = xp[t + 256];
        const u32* mp = mask + (size_t)b * 512;
        msk[t]       = (mp[t] != 0u);         // works for int32 0/1 and f32 0/1
        msk[t + 256] = (mp[t + 256] != 0u);
    }
    __syncthreads();

    // ---- phase B: conv1(4->32) + BN + ReLU + mask + 2x2x2 maxpool ----
    // thread: pooled site ps = t&63, cout group cg1 = t>>6 (8 couts each)
    {
        const int ps  = t & 63;
        const int cg1 = __builtin_amdgcn_readfirstlane(t >> 6);  // wave-uniform
        const int pz = ps >> 4, py = (ps >> 2) & 3, px = ps & 3;

        float pmax[8];
        #pragma unroll
        for (int j = 0; j < 8; ++j) pmax[j] = 0.f;
        int any = 0;

        for (int dz = 0; dz < 2; ++dz)
        for (int dy = 0; dy < 2; ++dy)
        for (int dx = 0; dx < 2; ++dx) {
            int z = 2 * pz + dz, y = 2 * py + dy, xx = 2 * px + dx;
            int s = z * 64 + y * 8 + xx;
            if (!msk[s]) continue;           // inactive site: exact 0 after relu*mask
            any = 1;
            float acc[8];
            #pragma unroll
            for (int j = 0; j < 8; ++j) acc[j] = 0.f;
            for (int kd = 0; kd < 3; ++kd) {
                int zz = z + kd - 1; if ((unsigned)zz >= 8u) continue;
                for (int kh = 0; kh < 3; ++kh) {
                    int yy = y + kh - 1; if ((unsigned)yy >= 8u) continue;
                    for (int kw = 0; kw < 3; ++kw) {
                        int xn = xx + kw - 1; if ((unsigned)xn >= 8u) continue;
                        int ns = zz * 64 + yy * 8 + xn;
                        int tap = (kd * 3 + kh) * 3 + kw;
                        const float* wp = W1 + tap * 128 + cg1 * 8;  // uniform
                        #pragma unroll
                        for (int ci = 0; ci < 4; ++ci) {
                            float hv = xs[ci * 512 + ns];
                            #pragma unroll
                            for (int j = 0; j < 8; ++j)
                                acc[j] += hv * wp[ci * 32 + j];
                        }
                    }
                }
            }
            #pragma unroll
            for (int j = 0; j < 8; ++j) {
                int co = cg1 * 8 + j;
                float vv = fmaxf(acc[j] * sc1s[co] + sh1s[co], 0.f);
                pmax[j] = fmaxf(pmax[j], vv);
            }
        }
        #pragma unroll
        for (int j = 0; j < 8; ++j)
            hs[(cg1 * 8 + j) * 65 + ps] = pmax[j];
        if (t < 64) mf2s[ps] = any ? 1.f : 0.f;
    }
    __syncthreads();

    // ---- phase C: conv2(32->64) + BN + ReLU + mask + 2x2x2 maxpool ----
    // thread: site s = t&63 (4x4x4), cout group cg = t>>6 (16 couts each)
    {
        const int s  = t & 63;
        const int cg = __builtin_amdgcn_readfirstlane(t >> 6);  // wave-uniform
        const int z = s >> 4, y = (s >> 2) & 3, xx = s & 3;

        float acc[16];
        #pragma unroll
        for (int j = 0; j < 16; ++j) acc[j] = 0.f;

        for (int kd = 0; kd < 3; ++kd) {
            int zz = z + kd - 1; bool vz = (unsigned)zz < 4u;
            for (int kh = 0; kh < 3; ++kh) {
                int yy = y + kh - 1; bool vy = vz && ((unsigned)yy < 4u);
                for (int kw = 0; kw < 3; ++kw) {
                    int xn = xx + kw - 1; bool v = vy && ((unsigned)xn < 4u);
                    int ns = v ? (zz * 16 + yy * 4 + xn) : 0;
                    float vf = v ? 1.f : 0.f;
                    int tap = (kd * 3 + kh) * 3 + kw;
                    const float* wp = W2 + tap * 2048 + cg * 16;  // uniform
                    #pragma unroll 4
                    for (int ci = 0; ci < 32; ++ci) {
                        float hv = hs[ci * 65 + ns] * vf;
                        #pragma unroll
                        for (int j = 0; j < 16; ++j)
                            acc[j] += hv * wp[ci * 64 + j];
                    }
                }
            }
        }

        const float mact = mf2s[s];
        const int pp = ((s >> 5) & 1) * 4 + ((s >> 3) & 1) * 2 + ((s >> 1) & 1);
        const bool writer = (s & 21) == 0;  // lsbs of x(bit0), y(bit2), z(bit4)

        #pragma unroll
        for (int j = 0; j < 16; ++j) {
            int co = cg * 16 + j;
            float vv = fmaxf(acc[j] * sc2s[co] + sh2s[co], 0.f) * mact;
            float p1 = fmaxf(vv, __shfl_xor(vv, 1, 64));    // pool x
            float p2 = fmaxf(p1, __shfl_xor(p1, 4, 64));    // pool y
            float p3 = fmaxf(p2, __shfl_xor(p2, 16, 64));   // pool z
            if (writer) h2s[co * 8 + pp] = p3;
        }
    }
    __syncthreads();

    // ---- phase D: FC 512->128 (LeakyReLU) -> 1 ----
    float p = 0.f;
    if (t < 128) {
        float acc = fcb1[t];
        const float4* wrow = (const float4*)(fcw1 + (size_t)t * 512);
        for (int kb = 0; kb < 128; ++kb) {
            float4 wv = wrow[kb];
            const float* hp = h2s + kb * 4;   // broadcast LDS read
            acc += hp[0] * wv.x + hp[1] * wv.y + hp[2] * wv.z + hp[3] * wv.w;
        }
        float a = (acc >= 0.f) ? acc : 0.01f * acc;  // LeakyReLU
        p = a * fcw2[t];
    }
    #pragma unroll
    for (int off = 32; off > 0; off >>= 1) p += __shfl_down(p, off, 64);
    if ((t & 63) == 0) red[t >> 6] = p;
    __syncthreads();
    if (t == 0)
        out[b] = red[0] + red[1] + red[2] + red[3] + fcb2[0];   // FLOAT32 output
}

extern "C" void kernel_launch(void* const* d_in, const int* in_sizes, int n_in,
                              void* d_out, int out_size, void* d_ws, size_t ws_size,
                              hipStream_t stream) {
    const float* x    = (const float*)d_in[0];
    const u32*   mask = (const u32*)d_in[1];
    const float* W1   = (const float*)d_in[2];
    const float* g1   = (const float*)d_in[3];
    const float* b1   = (const float*)d_in[4];
    const float* m1   = (const float*)d_in[5];
    const float* v1   = (const float*)d_in[6];
    const float* W2   = (const float*)d_in[7];
    const float* g2   = (const float*)d_in[8];
    const float* b2   = (const float*)d_in[9];
    const float* m2   = (const float*)d_in[10];
    const float* v2   = (const float*)d_in[11];
    const float* fcw1 = (const float*)d_in[12];
    const float* fcb1 = (const float*)d_in[13];
    const float* fcw2 = (const float*)d_in[14];
    const float* fcb2 = (const float*)d_in[15];
    float* out = (float*)d_out;

    fused_net_kernel<<<4096, 256, 0, stream>>>(
        x, mask, W1, g1, b1, m1, v1, W2, g2, b2, m2, v2,
        fcw1, fcb1, fcw2, fcb2, out);
}

// Round 6
// 390.021 us; speedup vs baseline: 1.6403x; 1.6403x over previous
//
#include <hip/hip_runtime.h>
#include <hip/hip_bf16.h>

typedef unsigned short u16;
typedef unsigned int   u32;
typedef short bf16x8 __attribute__((ext_vector_type(8)));
typedef float f32x4  __attribute__((ext_vector_type(4)));

#define EPS 1e-5f

__device__ __forceinline__ u16 f2bf(float f) {
    __hip_bfloat16 h = __float2bfloat16(f);
    return *(const u16*)&h;
}

// ---- prep: pack W2 f32 [tap][ci][cout] -> bf16 [tap][cout][ci] in ws ----
__global__ __launch_bounds__(256) void prep_w2_kernel(
        const float* __restrict__ W2, u16* __restrict__ w2b) {
    int i = blockIdx.x * 256 + threadIdx.x;   // i = tap*2048 + co*32 + ci
    if (i < 55296) {
        int tap = i >> 11, rem = i & 2047;
        int co = rem >> 5, ci = rem & 31;
        w2b[i] = f2bf(W2[(size_t)tap * 2048 + ci * 64 + co]);
    }
}

// One block per batch item b (grid 4096, block 256 = 4 waves).
// conv1: f32 VALU (as round 5). conv2: bf16 MFMA 16x16x32, wave = ntile(z),
// accumulating all 4 mtiles; A-frags from L2-resident w2b, B-frags from LDS.
__global__ __launch_bounds__(256) void fused_net_kernel(
        const float* __restrict__ x,    const u32*  __restrict__ mask,
        const float* __restrict__ W1,   const float* __restrict__ g1,
        const float* __restrict__ b1,   const float* __restrict__ m1,
        const float* __restrict__ v1,   const float* __restrict__ W2,
        const float* __restrict__ g2,   const float* __restrict__ b2,
        const float* __restrict__ m2,   const float* __restrict__ v2,
        const float* __restrict__ fcw1, const float* __restrict__ fcb1,
        const float* __restrict__ fcw2, const float* __restrict__ fcb2,
        const u16*  __restrict__ w2b,
        float* __restrict__ out) {

    __shared__ float xs[2048];                   // [ci(4)][site(512)]
    __shared__ int   msk[512];
    __shared__ __align__(16) u16 act16[65 * 40]; // [site(64)+zero-row][ci(32)+pad8]
    __shared__ float mf2s[64];
    __shared__ float h2pre[64 * 16];             // [cout][z(4)][py*2+px(4)] pre-z-pool
    __shared__ float hb[512];                    // pooled conv2 out for FC
    __shared__ float sc1s[32], sh1s[32], sc2s[64], sh2s[64];
    __shared__ float red[4];

    const int b = blockIdx.x;
    const int t = threadIdx.x;

    // ---- BN fold ----
    if (t < 32) {
        float sc = g1[t] / sqrtf(v1[t] + EPS);
        sc1s[t] = sc; sh1s[t] = b1[t] - m1[t] * sc;
    } else if (t < 96) {
        int c = t - 32;
        float sc = g2[c] / sqrtf(v2[c] + EPS);
        sc2s[c] = sc; sh2s[c] = b2[c] - m2[c] * sc;
    }

    // ---- stage x, mask; zero halo row of act16 ----
    {
        const float4* xp = (const float4*)(x + (size_t)b * 2048);
        ((float4*)xs)[t]       = xp[t];
        ((float4*)xs)[t + 256] = xp[t + 256];
        const u32* mp = mask + (size_t)b * 512;
        msk[t]       = (mp[t] != 0u);
        msk[t + 256] = (mp[t + 256] != 0u);
        if (t < 20) ((u32*)act16)[64 * 20 + t] = 0u;   // zero row 64
    }
    __syncthreads();

    // ---- phase B: conv1(4->32) + BN + ReLU + mask + 2x2x2 maxpool (f32) ----
    // thread: pooled site ps = t&63, cout group cg1 = t>>6 (8 couts each)
    {
        const int ps  = t & 63;
        const int cg1 = __builtin_amdgcn_readfirstlane(t >> 6);
        const int pz = ps >> 4, py = (ps >> 2) & 3, px = ps & 3;

        float pmax[8];
        #pragma unroll
        for (int j = 0; j < 8; ++j) pmax[j] = 0.f;
        int any = 0;

        for (int dz = 0; dz < 2; ++dz)
        for (int dy = 0; dy < 2; ++dy)
        for (int dx = 0; dx < 2; ++dx) {
            int z = 2 * pz + dz, y = 2 * py + dy, xx = 2 * px + dx;
            int s = z * 64 + y * 8 + xx;
            if (!msk[s]) continue;
            any = 1;
            float acc[8];
            #pragma unroll
            for (int j = 0; j < 8; ++j) acc[j] = 0.f;
            for (int kd = 0; kd < 3; ++kd) {
                int zz = z + kd - 1; if ((unsigned)zz >= 8u) continue;
                for (int kh = 0; kh < 3; ++kh) {
                    int yy = y + kh - 1; if ((unsigned)yy >= 8u) continue;
                    for (int kw = 0; kw < 3; ++kw) {
                        int xn = xx + kw - 1; if ((unsigned)xn >= 8u) continue;
                        int ns = zz * 64 + yy * 8 + xn;
                        int tap = (kd * 3 + kh) * 3 + kw;
                        const float* wp = W1 + tap * 128 + cg1 * 8;  // uniform
                        #pragma unroll
                        for (int ci = 0; ci < 4; ++ci) {
                            float hv = xs[ci * 512 + ns];
                            #pragma unroll
                            for (int j = 0; j < 8; ++j)
                                acc[j] += hv * wp[ci * 32 + j];
                        }
                    }
                }
            }
            #pragma unroll
            for (int j = 0; j < 8; ++j) {
                int co = cg1 * 8 + j;
                float vv = fmaxf(acc[j] * sc1s[co] + sh1s[co], 0.f);
                pmax[j] = fmaxf(pmax[j], vv);
            }
        }
        // write bf16 activation row [ps][cg1*8 .. +7], packed as 4 u32
        #pragma unroll
        for (int jj = 0; jj < 4; ++jj) {
            u32 lo = f2bf(pmax[2 * jj]), hi = f2bf(pmax[2 * jj + 1]);
            ((u32*)act16)[ps * 20 + cg1 * 4 + jj] = lo | (hi << 16);
        }
        if (t < 64) mf2s[ps] = any ? 1.f : 0.f;
    }
    __syncthreads();

    // ---- phase C: conv2(32->64) via bf16 MFMA 16x16x32 ----
    // wave w = ntile = z-slice; lane: n = site col (lane&15), quad = lane>>4.
    // A[m=lane&15=cout_local][k=quad*8+j] from w2b[tap][cout][ci] (coalesced).
    // B[k=quad*8+j][n] from act16[site][ci] row (ds_read_b128).
    // D[m=quad*4+reg][n=lane&15] (m89-verified C-layout).
    {
        const int w    = __builtin_amdgcn_readfirstlane(t >> 6);  // z = ntile
        const int lane = t & 63;
        const int n    = lane & 15;
        const int quad = lane >> 4;
        const int yv = n >> 2, xv = n & 3;

        f32x4 acc[4];
        #pragma unroll
        for (int mt = 0; mt < 4; ++mt) acc[mt] = (f32x4){0.f, 0.f, 0.f, 0.f};

        for (int kd = 0; kd < 3; ++kd) {
            int zz = w + kd - 1;
            if ((unsigned)zz >= 4u) continue;          // wave-uniform skip
            #pragma unroll
            for (int kh = 0; kh < 3; ++kh) {
                int yy = yv + kh - 1; bool vy = (unsigned)yy < 4u;
                #pragma unroll
                for (int kw = 0; kw < 3; ++kw) {
                    int xn = xv + kw - 1; bool v = vy && ((unsigned)xn < 4u);
                    int row = v ? (zz * 16 + yy * 4 + xn) : 64;   // 64 = zero row
                    int tap = (kd * 3 + kh) * 3 + kw;
                    bf16x8 bfrag = *(const bf16x8*)(act16 + row * 40 + quad * 8);
                    const u16* ap = w2b + tap * 2048 + n * 32 + quad * 8;
                    #pragma unroll
                    for (int mt = 0; mt < 4; ++mt) {
                        bf16x8 afrag = *(const bf16x8*)(ap + mt * 512);
                        acc[mt] = __builtin_amdgcn_mfma_f32_16x16x32_bf16(
                                      afrag, bfrag, acc[mt], 0, 0, 0);
                    }
                }
            }
        }

        // epilogue: BN + ReLU + mask, pool x (shfl1) + y (shfl4); z-pool deferred
        const float mact = mf2s[w * 16 + n];
        #pragma unroll
        for (int mt = 0; mt < 4; ++mt) {
            #pragma unroll
            for (int r = 0; r < 4; ++r) {
                int cout = mt * 16 + quad * 4 + r;
                float val = fmaxf(acc[mt][r] * sc2s[cout] + sh2s[cout], 0.f) * mact;
                float p1 = fmaxf(val, __shfl_xor(val, 1, 64));   // pool x
                float p2 = fmaxf(p1,  __shfl_xor(p1, 4, 64));    // pool y
                if ((n & 5) == 0)
                    h2pre[cout * 16 + w * 4 + ((n >> 3) & 1) * 2 + ((n >> 1) & 1)] = p2;
            }
        }
    }
    __syncthreads();

    // ---- z-pool into hb [co*8 + pz*4+py*2+px] ----
    for (int i = t; i < 512; i += 256) {
        int co = i >> 3, pp = i & 7;
        int pz = pp >> 2, py = (pp >> 1) & 1, px = pp & 1;
        int base = co * 16 + py * 2 + px;
        hb[i] = fmaxf(h2pre[base + (2 * pz) * 4], h2pre[base + (2 * pz + 1) * 4]);
    }
    __syncthreads();

    // ---- phase D: FC 512->128 (LeakyReLU) -> 1 ----
    float p = 0.f;
    if (t < 128) {
        float acc = fcb1[t];
        const float4* wrow = (const float4*)(fcw1 + (size_t)t * 512);
        for (int kb = 0; kb < 128; ++kb) {
            float4 wv = wrow[kb];
            const float* hp = hb + kb * 4;   // broadcast LDS read
            acc += hp[0] * wv.x + hp[1] * wv.y + hp[2] * wv.z + hp[3] * wv.w;
        }
        float a = (acc >= 0.f) ? acc : 0.01f * acc;  // LeakyReLU
        p = a * fcw2[t];
    }
    #pragma unroll
    for (int off = 32; off > 0; off >>= 1) p += __shfl_down(p, off, 64);
    if ((t & 63) == 0) red[t >> 6] = p;
    __syncthreads();
    if (t == 0)
        out[b] = red[0] + red[1] + red[2] + red[3] + fcb2[0];   // f32 output
}

extern "C" void kernel_launch(void* const* d_in, const int* in_sizes, int n_in,
                              void* d_out, int out_size, void* d_ws, size_t ws_size,
                              hipStream_t stream) {
    const float* x    = (const float*)d_in[0];
    const u32*   mask = (const u32*)d_in[1];
    const float* W1   = (const float*)d_in[2];
    const float* g1   = (const float*)d_in[3];
    const float* b1   = (const float*)d_in[4];
    const float* m1   = (const float*)d_in[5];
    const float* v1   = (const float*)d_in[6];
    const float* W2   = (const float*)d_in[7];
    const float* g2   = (const float*)d_in[8];
    const float* b2   = (const float*)d_in[9];
    const float* m2   = (const float*)d_in[10];
    const float* v2   = (const float*)d_in[11];
    const float* fcw1 = (const float*)d_in[12];
    const float* fcb1 = (const float*)d_in[13];
    const float* fcw2 = (const float*)d_in[14];
    const float* fcb2 = (const float*)d_in[15];
    u16*   w2b = (u16*)d_ws;            // 55296 u16 = 110,592 B of ws
    float* out = (float*)d_out;

    prep_w2_kernel<<<216, 256, 0, stream>>>(W2, w2b);
    fused_net_kernel<<<4096, 256, 0, stream>>>(
        x, mask, W1, g1, b1, m1, v1, W2, g2, b2, m2, v2,
        fcw1, fcb1, fcw2, fcb2, w2b, out);
}

// Round 7
// 329.572 us; speedup vs baseline: 1.9412x; 1.1834x over previous
//
#include <hip/hip_runtime.h>
#include <hip/hip_bf16.h>

typedef unsigned short u16;
typedef unsigned int   u32;
typedef short bf16x8 __attribute__((ext_vector_type(8)));
typedef short bf16x4 __attribute__((ext_vector_type(4)));
typedef float f32x4  __attribute__((ext_vector_type(4)));

#define EPS 1e-5f

__device__ __forceinline__ u16 f2bf(float f) {
    __hip_bfloat16 h = __float2bfloat16(f);
    return *(const u16*)&h;
}

union BV { bf16x8 v; bf16x4 h[2]; };

// ---- prep: pack W2 -> bf16 [tap][cout][ci]; W1 -> bf16 [ks][quad][cout][8] ----
// w1b slot j of 8: tap = ks*8 + quad*2 + (j>>2), ci = j&3 (k = tap*4+ci packing),
// zero for tap >= 27.
__global__ __launch_bounds__(256) void prep_kernel(
        const float* __restrict__ W2, const float* __restrict__ W1,
        u16* __restrict__ w2b, u16* __restrict__ w1b) {
    int i = blockIdx.x * 256 + threadIdx.x;
    if (i < 55296) {
        int tap = i >> 11, rem = i & 2047;
        int co = rem >> 5, ci = rem & 31;
        w2b[i] = f2bf(W2[(size_t)tap * 2048 + ci * 64 + co]);
    }
    if (i < 4096) {   // i = ((ks*4+quad)*32 + cout)*8 + j
        int j = i & 7, cout = (i >> 3) & 31, quad = (i >> 8) & 3, ks = i >> 10;
        int tap = ks * 8 + quad * 2 + (j >> 2), ci = j & 3;
        w1b[i] = (tap < 27) ? f2bf(W1[tap * 128 + ci * 32 + cout]) : (u16)0;
    }
}

// One block per batch item (grid 4096, block 256 = 4 waves). Both convs via
// bf16 MFMA 16x16x32. conv1: wave = 2 z-slices (8 ntiles of the 512-site GEMM),
// K=128 (27 taps x 4 ci, padded); conv2: wave = z-slice as round 6.
__global__ __launch_bounds__(256) void fused_net_kernel(
        const float* __restrict__ x,    const u32*  __restrict__ mask,
        const float* __restrict__ g1,   const float* __restrict__ b1,
        const float* __restrict__ m1,   const float* __restrict__ v1,
        const float* __restrict__ g2,   const float* __restrict__ b2,
        const float* __restrict__ m2,   const float* __restrict__ v2,
        const float* __restrict__ fcw1, const float* __restrict__ fcb1,
        const float* __restrict__ fcw2, const float* __restrict__ fcb2,
        const u16*  __restrict__ w2b,  const u16* __restrict__ w1b,
        float* __restrict__ out) {

    __shared__ __align__(16) u16 xb[513 * 4];     // [site(512)+zero][ci(4)] bf16
    __shared__ int   msk[512];
    __shared__ float h1mid[128 * 33];             // [z(8)·py(4)·px(4)][cout(32)] +pad
    __shared__ __align__(16) u16 act16[65 * 40];  // [ps(64)+zero][ci(32)+pad]
    __shared__ float mf2s[64];
    __shared__ float h2pre[64 * 16];              // [cout][z(4)][py2·px2(4)]
    __shared__ float hb[512];
    __shared__ float sc1s[32], sh1s[32], sc2s[64], sh2s[64];
    __shared__ float red[4];

    const int b = blockIdx.x;
    const int t = threadIdx.x;

    // ---- BN fold ----
    if (t < 32) {
        float sc = g1[t] / sqrtf(v1[t] + EPS);
        sc1s[t] = sc; sh1s[t] = b1[t] - m1[t] * sc;
    } else if (t < 96) {
        int c = t - 32;
        float sc = g2[c] / sqrtf(v2[c] + EPS);
        sc2s[c] = sc; sh2s[c] = b2[c] - m2[c] * sc;
    }

    // ---- stage x -> bf16 [site][ci]; mask; zero rows ----
    {
        const float* xp = x + (size_t)b * 2048;
        const u32*   mp = mask + (size_t)b * 512;
        for (int s = t; s < 512; s += 256) {
            float a0 = xp[s], a1 = xp[512 + s], a2 = xp[1024 + s], a3 = xp[1536 + s];
            ((u32*)xb)[s * 2]     = (u32)f2bf(a0) | ((u32)f2bf(a1) << 16);
            ((u32*)xb)[s * 2 + 1] = (u32)f2bf(a2) | ((u32)f2bf(a3) << 16);
            msk[s] = (mp[s] != 0u);
        }
        if (t < 2)  ((u32*)xb)[1024 + t] = 0u;            // zero row 512
        if (t < 20) ((u32*)act16)[64 * 20 + t] = 0u;      // zero row 64
    }
    __syncthreads();

    const int lane = t & 63;
    const int n    = lane & 15;
    const int quad = lane >> 4;
    const int w    = __builtin_amdgcn_readfirstlane(t >> 6);

    // ---- phase B: conv1(4->32) via MFMA; wave covers sites [w*128, w*128+128) ----
    {
        const int xcoord = n & 7;      // x of site
        const int ylsb   = n >> 3;     // y lsb

        // preload A-frags: afr[ks][mt] (global, L2-resident, coalesced 16B)
        bf16x8 afr[4][2];
        #pragma unroll
        for (int ks = 0; ks < 4; ++ks)
            #pragma unroll
            for (int mt = 0; mt < 2; ++mt)
                afr[ks][mt] = *(const bf16x8*)(w1b +
                    (((ks * 4 + quad) * 32) + mt * 16 + n) * 8);

        // per-lane tap constants: q = ks*2 + tapl
        int doff_[8], kdm1_[8], khm1_[8]; bool vx_[8];
        #pragma unroll
        for (int q = 0; q < 8; ++q) {
            int tap = (q >> 1) * 8 + quad * 2 + (q & 1);
            bool tv = tap < 27;
            int tc = tv ? tap : 26;
            int kd = tc / 9, rr = tc - kd * 9, kh = rr / 3, kw = rr - kh * 3;
            int xn = xcoord + kw - 1;
            vx_[q]   = tv && ((unsigned)xn < 8u);
            doff_[q] = (kd - 1) * 64 + (kh - 1) * 8 + (kw - 1);
            kdm1_[q] = kd - 1; khm1_[q] = kh - 1;
        }

        #pragma unroll
        for (int i = 0; i < 8; ++i) {          // ntile
            const int s = (w * 8 + i) * 16 + n;
            const int z = w * 2 + (i >> 2);
            const int y = (i & 3) * 2 + ylsb;

            f32x4 acc0 = (f32x4){0.f, 0.f, 0.f, 0.f};
            f32x4 acc1 = (f32x4){0.f, 0.f, 0.f, 0.f};

            #pragma unroll
            for (int ks = 0; ks < 4; ++ks) {
                int qA = ks * 2, qB = qA + 1;
                int zzA = z + kdm1_[qA], yyA = y + khm1_[qA];
                int zzB = z + kdm1_[qB], yyB = y + khm1_[qB];
                bool vA = vx_[qA] && ((unsigned)zzA < 8u) && ((unsigned)yyA < 8u);
                bool vB = vx_[qB] && ((unsigned)zzB < 8u) && ((unsigned)yyB < 8u);
                int rA = vA ? (s + doff_[qA]) : 512;
                int rB = vB ? (s + doff_[qB]) : 512;
                BV bv;
                bv.h[0] = *(const bf16x4*)(xb + rA * 4);
                bv.h[1] = *(const bf16x4*)(xb + rB * 4);
                acc0 = __builtin_amdgcn_mfma_f32_16x16x32_bf16(afr[ks][0], bv.v, acc0, 0, 0, 0);
                acc1 = __builtin_amdgcn_mfma_f32_16x16x32_bf16(afr[ks][1], bv.v, acc1, 0, 0, 0);
            }

            // epilogue: BN+ReLU+mask, pool x (shfl1) + y (shfl8); write h1mid
            const float mk = msk[s] ? 1.f : 0.f;
            const int hrow = (z * 16 + (i & 3) * 4 + (n >> 1)) * 33;
            #pragma unroll
            for (int mt = 0; mt < 2; ++mt) {
                f32x4 a = mt ? acc1 : acc0;
                #pragma unroll
                for (int r = 0; r < 4; ++r) {
                    int cout = mt * 16 + quad * 4 + r;
                    float val = fmaxf(a[r] * sc1s[cout] + sh1s[cout], 0.f) * mk;
                    float p1 = fmaxf(val, __shfl_xor(val, 1, 64));
                    float p2 = fmaxf(p1,  __shfl_xor(p1, 8, 64));
                    if ((n & 9) == 0) h1mid[hrow + cout] = p2;
                }
            }
        }
    }
    __syncthreads();

    // ---- z-pool conv1 -> act16 bf16 [ps][ci]; mf2s from msk ----
    for (int idx = t; idx < 1024; idx += 256) {
        int ps = idx >> 4, jj = idx & 15;
        int pz = ps >> 4, py = (ps >> 2) & 3, px = ps & 3;
        int rA = ((2 * pz) * 16 + py * 4 + px) * 33;
        int rB = rA + 16 * 33;
        float v0 = fmaxf(h1mid[rA + 2 * jj],     h1mid[rB + 2 * jj]);
        float v1 = fmaxf(h1mid[rA + 2 * jj + 1], h1mid[rB + 2 * jj + 1]);
        ((u32*)act16)[ps * 20 + jj] = (u32)f2bf(v0) | ((u32)f2bf(v1) << 16);
    }
    if (t < 64) {
        int pz = t >> 4, py = (t >> 2) & 3, px = t & 3;
        int a = 0;
        #pragma unroll
        for (int dz = 0; dz < 2; ++dz)
            #pragma unroll
            for (int dy = 0; dy < 2; ++dy)
                #pragma unroll
                for (int dx = 0; dx < 2; ++dx)
                    a |= msk[(2 * pz + dz) * 64 + (2 * py + dy) * 8 + (2 * px + dx)];
        mf2s[t] = a ? 1.f : 0.f;
    }
    __syncthreads();

    // ---- phase C: conv2(32->64) via MFMA (round-6 validated) ----
    {
        const int yv = n >> 2, xv = n & 3;

        f32x4 acc[4];
        #pragma unroll
        for (int mt = 0; mt < 4; ++mt) acc[mt] = (f32x4){0.f, 0.f, 0.f, 0.f};

        for (int kd = 0; kd < 3; ++kd) {
            int zz = w + kd - 1;
            if ((unsigned)zz >= 4u) continue;          // wave-uniform skip
            #pragma unroll
            for (int kh = 0; kh < 3; ++kh) {
                int yy = yv + kh - 1; bool vy = (unsigned)yy < 4u;
                #pragma unroll
                for (int kw = 0; kw < 3; ++kw) {
                    int xn = xv + kw - 1; bool v = vy && ((unsigned)xn < 4u);
                    int row = v ? (zz * 16 + yy * 4 + xn) : 64;
                    int tap = (kd * 3 + kh) * 3 + kw;
                    bf16x8 bfrag = *(const bf16x8*)(act16 + row * 40 + quad * 8);
                    const u16* ap = w2b + tap * 2048 + n * 32 + quad * 8;
                    #pragma unroll
                    for (int mt = 0; mt < 4; ++mt) {
                        bf16x8 afrag = *(const bf16x8*)(ap + mt * 512);
                        acc[mt] = __builtin_amdgcn_mfma_f32_16x16x32_bf16(
                                      afrag, bfrag, acc[mt], 0, 0, 0);
                    }
                }
            }
        }

        const float mact = mf2s[w * 16 + n];
        #pragma unroll
        for (int mt = 0; mt < 4; ++mt) {
            #pragma unroll
            for (int r = 0; r < 4; ++r) {
                int cout = mt * 16 + quad * 4 + r;
                float val = fmaxf(acc[mt][r] * sc2s[cout] + sh2s[cout], 0.f) * mact;
                float p1 = fmaxf(val, __shfl_xor(val, 1, 64));
                float p2 = fmaxf(p1,  __shfl_xor(p1, 4, 64));
                if ((n & 5) == 0)
                    h2pre[cout * 16 + w * 4 + ((n >> 3) & 1) * 2 + ((n >> 1) & 1)] = p2;
            }
        }
    }
    __syncthreads();

    // ---- z-pool conv2 -> hb [co*8 + pz*4+py*2+px] ----
    for (int i = t; i < 512; i += 256) {
        int co = i >> 3, pp = i & 7;
        int pz = pp >> 2, py = (pp >> 1) & 1, px = pp & 1;
        int base = co * 16 + py * 2 + px;
        hb[i] = fmaxf(h2pre[base + (2 * pz) * 4], h2pre[base + (2 * pz + 1) * 4]);
    }
    __syncthreads();

    // ---- phase D: FC 512->128 (LeakyReLU) -> 1 ----
    float p = 0.f;
    if (t < 128) {
        float acc = fcb1[t];
        const float4* wrow = (const float4*)(fcw1 + (size_t)t * 512);
        for (int kb = 0; kb < 128; ++kb) {
            float4 wv = wrow[kb];
            const float* hp = hb + kb * 4;
            acc += hp[0] * wv.x + hp[1] * wv.y + hp[2] * wv.z + hp[3] * wv.w;
        }
        float a = (acc >= 0.f) ? acc : 0.01f * acc;
        p = a * fcw2[t];
    }
    #pragma unroll
    for (int off = 32; off > 0; off >>= 1) p += __shfl_down(p, off, 64);
    if ((t & 63) == 0) red[t >> 6] = p;
    __syncthreads();
    if (t == 0)
        out[b] = red[0] + red[1] + red[2] + red[3] + fcb2[0];
}

extern "C" void kernel_launch(void* const* d_in, const int* in_sizes, int n_in,
                              void* d_out, int out_size, void* d_ws, size_t ws_size,
                              hipStream_t stream) {
    const float* x    = (const float*)d_in[0];
    const u32*   mask = (const u32*)d_in[1];
    const float* W1   = (const float*)d_in[2];
    const float* g1   = (const float*)d_in[3];
    const float* b1   = (const float*)d_in[4];
    const float* m1   = (const float*)d_in[5];
    const float* v1   = (const float*)d_in[6];
    const float* W2   = (const float*)d_in[7];
    const float* g2   = (const float*)d_in[8];
    const float* b2   = (const float*)d_in[9];
    const float* m2   = (const float*)d_in[10];
    const float* v2   = (const float*)d_in[11];
    const float* fcw1 = (const float*)d_in[12];
    const float* fcb1 = (const float*)d_in[13];
    const float* fcw2 = (const float*)d_in[14];
    const float* fcb2 = (const float*)d_in[15];
    u16* w2b = (u16*)d_ws;              // 55296 u16
    u16* w1b = w2b + 55296;             // 4096 u16 (16B-aligned offset)
    float* out = (float*)d_out;

    prep_kernel<<<216, 256, 0, stream>>>(W2, W1, w2b, w1b);
    fused_net_kernel<<<4096, 256, 0, stream>>>(
        x, mask, g1, b1, m1, v1, g2, b2, m2, v2,
        fcw1, fcb1, fcw2, fcb2, w2b, w1b, out);
}